// Round 3
// baseline (422.930 us; speedup 1.0000x reference)
//
#include <hip/hip_runtime.h>

#define B_ 8
#define T_ 4096
#define W_ 1024
#define H_ 8
#define BW_ 128
#define M_ 128          // timesteps per chunk
#define NC_ 32          // chunks per sequence (T_/M_)
#define XS 136          // LDS row stride (halves): 272B rows
#define NS_ 8           // 16-step segments per chunk

typedef __attribute__((ext_vector_type(8))) short bf16x8;
typedef __attribute__((ext_vector_type(4))) float f32x4;

__device__ __forceinline__ float bf2f(unsigned short u) {
    return __uint_as_float(((unsigned)u) << 16);
}
__device__ __forceinline__ unsigned short f2bf(float f) {
    unsigned u = __float_as_uint(f);
    u += 0x7fffu + ((u >> 16) & 1u);       // round-nearest-even
    return (unsigned short)(u >> 16);
}
__device__ __forceinline__ unsigned short f2h_bits(float f) {
    union { _Float16 h; unsigned short u; } cv;
    cv.h = (_Float16)f;
    return cv.u;
}
__device__ __forceinline__ float h2f(unsigned short u) {
    union { _Float16 h; unsigned short u; } cv;
    cv.u = u;
    return (float)cv.h;
}
__device__ __forceinline__ float sigmoidf_(float z) {
    return 1.0f / (1.0f + __expf(-z));
}

// ---------------- prep: fp32 weights -> transposed bf16 [h][j][i] in ws; cj = -8*softplus(a_param)
__global__ __launch_bounds__(256) void prep_kernel(
    const float* __restrict__ w_in, const float* __restrict__ w_a,
    const float* __restrict__ a_param,
    unsigned short* __restrict__ wt_in, unsigned short* __restrict__ wt_a,
    float* __restrict__ cj)
{
    int gid = blockIdx.x * 256 + threadIdx.x;     // 0..32767
    if (gid < W_) {
        float ap = a_param[gid];
        cj[gid] = -8.0f * log1pf(__expf(ap));
    }
    int mat  = gid >> 14;          // 0: w_in, 1: w_a
    int rem  = gid & 16383;
    int hh   = rem >> 11;          // head
    int r2   = rem & 2047;
    int seg  = r2 >> 7;            // i-segment (8 elems)
    int jrow = r2 & 127;           // output row j (low bits -> coalesced fp32 reads)
    const float* src = (mat ? w_a : w_in) + hh * BW_ * BW_;
    unsigned short* dst = (mat ? wt_a : wt_in) + hh * BW_ * BW_;
    unsigned short tmp[8] __attribute__((aligned(16)));
    #pragma unroll
    for (int k = 0; k < 8; ++k) tmp[k] = f2bf(src[(seg * 8 + k) * BW_ + jrow]);
    *(uint4*)(dst + jrow * BW_ + seg * 8) = *(const uint4*)tmp;
}

// ---------------- K1: gates (MFMA) + elementwise, computed ONCE.
// LDS slim (~44 KB -> 2 blocks/CU): W-fragments from L2-hot global, packed (a|nx)
// stored directly from registers (chunk-blocked layout), 4->16 step combine via shfl.
__global__ __launch_bounds__(1024, 8) void rg_gates(
    const float* __restrict__ x,
    const unsigned short* __restrict__ wt_in,
    const unsigned short* __restrict__ wt_a,
    const float* __restrict__ b_in,
    const float* __restrict__ b_a,
    const float* __restrict__ cj,
    float* __restrict__ aggA, float* __restrict__ aggE,
    unsigned int* __restrict__ packed)
{
    __shared__ alignas(16) unsigned short Xs[M_ * XS];    // 34816 B: x bf16
    __shared__ float2 S2[NS_ * BW_];                      //  8192 B: 16-step (A,E)
    __shared__ float cj_s[BW_], ba_s[BW_], bi_s[BW_];     //  1536 B

    const int tid = threadIdx.x;
    const int bid = blockIdx.x;
    const int c = bid & (NC_ - 1);
    const int s = bid >> 5;
    const int b = s >> 3;
    const int h = s & 7;
    const int t0 = c * M_;

    const float* xg = x + ((size_t)b * T_ + t0) * W_ + h * BW_;

    // stage X tile (fp32 -> bf16), coalesced 512B rows
    #pragma unroll
    for (int r = 0; r < 4; ++r) {
        int u = tid + r * 1024;        // 0..4095
        int t = u >> 5, sg = u & 31;   // 4 floats per sg
        const float4 v = *(const float4*)(xg + (size_t)t * W_ + sg * 4);
        ushort4 hv;
        hv.x = f2bf(v.x); hv.y = f2bf(v.y); hv.z = f2bf(v.z); hv.w = f2bf(v.w);
        *(ushort4*)&Xs[t * XS + sg * 4] = hv;
    }
    if (tid < BW_) {
        cj_s[tid] = cj[h * BW_ + tid];
        ba_s[tid] = b_a[h * BW_ + tid];
        bi_s[tid] = b_in[h * BW_ + tid];
    }
    __syncthreads();

    const int wave = tid >> 6;
    const int lane = tid & 63;
    const int q  = lane >> 4;
    const int cl = lane & 15;
    const int mw = wave >> 1;       // 0..7: 16-row group
    const int nw = wave & 1;        // 0..1: 64-col half

    const unsigned short* wag = wt_a  + h * BW_ * BW_;
    const unsigned short* wig = wt_in + h * BW_ * BW_;

    f32x4 zero4 = {0.0f, 0.0f, 0.0f, 0.0f};
    f32x4 acc_a[4], acc_x[4];
    #pragma unroll
    for (int nt = 0; nt < 4; ++nt) { acc_a[nt] = zero4; acc_x[nt] = zero4; }

    // both gate passes interleaved; A-fragment transient per kk (low VGPR)
    #pragma unroll
    for (int kk = 0; kk < 4; ++kk) {
        bf16x8 af = *(const bf16x8*)&Xs[(mw * 16 + cl) * XS + kk * 32 + q * 8];
        #pragma unroll
        for (int nt = 0; nt < 4; ++nt) {
            int j = nw * 64 + nt * 16 + cl;
            size_t wo = (size_t)j * BW_ + kk * 32 + q * 8;   // 64B-contiguous per 4 lanes
            bf16x8 bfa = *(const bf16x8*)(wag + wo);
            acc_a[nt] = __builtin_amdgcn_mfma_f32_16x16x32_bf16(af, bfa, acc_a[nt], 0, 0, 0);
            bf16x8 bfi = *(const bf16x8*)(wig + wo);
            acc_x[nt] = __builtin_amdgcn_mfma_f32_16x16x32_bf16(af, bfi, acc_x[nt], 0, 0, 0);
        }
    }

    // elementwise + packed store + shfl combine (4-step -> 16-step)
    unsigned int* pgc = packed + (((size_t)s * NC_ + c) * M_) * BW_;
    #pragma unroll
    for (int nt = 0; nt < 4; ++nt) {
        int j = nw * 64 + nt * 16 + cl;
        float cjv = cj_s[j], bav = ba_s[j], biv = bi_s[j];
        float A4 = 1.0f, E4 = 0.0f;
        #pragma unroll
        for (int r = 0; r < 4; ++r) {
            int tl = mw * 16 + q * 4 + r;                       // C/D layout: row = q*4 + r
            float la = cjv * sigmoidf_(acc_a[nt][r] + bav);     // log_a <= 0
            float a  = __expf(la);
            float gx = sigmoidf_(acc_x[nt][r] + biv);
            float xv = bf2f(Xs[tl * XS + j]);
            float mult = sqrtf(fmaxf(1.0f - a * a, 0.0f));
            if (t0 + tl == 0) { a = 0.0f; mult = 1.0f; }        // reset at global t=0
            float nxv = xv * gx * mult;
            unsigned short nxb = f2h_bits(nxv);
            float nxr = h2f(nxb);
            E4 = fmaf(a, E4, nxr);
            A4 *= a;
            pgc[(size_t)tl * BW_ + j] = ((unsigned int)f2h_bits(a) << 16) | (unsigned int)nxb;
        }
        // combine across q (lanes 16 apart): stage 1 pairs (q0,q1),(q2,q3); stage 2 full
        float Ap = __shfl_xor(A4, 16);
        float Ep = __shfl_xor(E4, 16);
        float E8 = ((lane >> 4) & 1) ? fmaf(A4, Ep, E4) : fmaf(Ap, E4, Ep);
        float A8 = A4 * Ap;
        Ap = __shfl_xor(A8, 32);
        Ep = __shfl_xor(E8, 32);
        float E16 = ((lane >> 5) & 1) ? fmaf(A8, Ep, E8) : fmaf(Ap, E8, Ep);
        float A16 = A8 * Ap;
        if ((lane >> 4) == 0) S2[mw * BW_ + j] = make_float2(A16, E16);
    }
    __syncthreads();

    // chunk aggregate write
    if (tid < BW_) {
        float At = 1.0f, Et = 0.0f;
        #pragma unroll
        for (int s8 = 0; s8 < NS_; ++s8) {
            float2 v = S2[s8 * BW_ + tid];
            Et = fmaf(v.x, Et, v.y);
            At *= v.x;
        }
        size_t idx = ((size_t)s * NC_ + c) * BW_ + tid;
        aggA[idx] = At;
        aggE[idx] = Et;
    }
}

// ---------------- K2: streaming scan + replay; per-block carry fold (no carry_scan kernel)
__global__ __launch_bounds__(1024, 8) void rg_scan(
    const unsigned int* __restrict__ packed,
    const float* __restrict__ aggA, const float* __restrict__ aggE,
    float* __restrict__ y)
{
    __shared__ float2 S2[NS_ * BW_];
    __shared__ float qin[NS_ * BW_];

    const int tid = threadIdx.x;
    const int bid = blockIdx.x;
    const int c = bid & (NC_ - 1);
    const int s = bid >> 5;
    const int b = s >> 3;
    const int h = s & 7;

    // chunk-blocked packed: contiguous 64KB per block
    const unsigned int* pg = packed + (((size_t)s * NC_ + c) * M_) * BW_;
    const int j  = tid & 127;
    const int qq = tid >> 7;        // 16-step segment

    unsigned int v[16];
    #pragma unroll
    for (int i = 0; i < 16; ++i)
        v[i] = pg[(size_t)(qq * 16 + i) * BW_ + j];

    float A = 1.0f, E = 0.0f;
    #pragma unroll
    for (int i = 0; i < 16; ++i) {
        float a  = h2f((unsigned short)(v[i] >> 16));
        float nx = h2f((unsigned short)(v[i] & 0xffffu));
        E = fmaf(a, E, nx);
        A *= a;
    }
    S2[qq * BW_ + j] = make_float2(A, E);
    __syncthreads();

    if (tid < BW_) {
        // fold chunk aggregates 0..c-1 (identical order to old carry_scan)
        const float* pA = aggA + ((size_t)s * NC_) * BW_ + tid;
        const float* pE = aggE + ((size_t)s * NC_) * BW_ + tid;
        float hh = 0.0f;
        for (int cc = 0; cc < c; ++cc)
            hh = fmaf(pA[(size_t)cc * BW_], hh, pE[(size_t)cc * BW_]);
        #pragma unroll
        for (int s8 = 0; s8 < NS_; ++s8) {
            qin[s8 * BW_ + tid] = hh;
            float2 w = S2[s8 * BW_ + tid];
            hh = fmaf(w.x, hh, w.y);
        }
    }
    __syncthreads();

    float hcur = qin[qq * BW_ + j];
    float* yg = y + ((size_t)b * T_ + c * M_) * W_ + h * BW_ + j;
    #pragma unroll
    for (int i = 0; i < 16; ++i) {
        float a  = h2f((unsigned short)(v[i] >> 16));
        float nx = h2f((unsigned short)(v[i] & 0xffffu));
        hcur = fmaf(a, hcur, nx);
        yg[(size_t)(qq * 16 + i) * W_] = hcur;     // coalesced across j lanes
    }
}

extern "C" void kernel_launch(void* const* d_in, const int* in_sizes, int n_in,
                              void* d_out, int out_size, void* d_ws, size_t ws_size,
                              hipStream_t stream)
{
    const float* x     = (const float*)d_in[0];
    const float* w_in  = (const float*)d_in[1];
    const float* b_in  = (const float*)d_in[2];
    const float* w_a   = (const float*)d_in[3];
    const float* b_a   = (const float*)d_in[4];
    const float* a_par = (const float*)d_in[5];
    float* y = (float*)d_out;

    char* ws = (char*)d_ws;
    unsigned short* wt_in = (unsigned short*)(ws);
    unsigned short* wt_a  = (unsigned short*)(ws + 262144);
    float* cj    = (float*)(ws + 524288);
    float* aggA  = (float*)(ws + 528384);
    float* aggE  = (float*)(ws + 1576960);
    unsigned int* packed = (unsigned int*)(ws + 2625536);

    const size_t NEED = 2625536ull + (size_t)B_ * T_ * W_ * 4ull;   // +128 MB packed
    if (ws_size < NEED) return;

    prep_kernel<<<dim3(128), dim3(256), 0, stream>>>(w_in, w_a, a_par, wt_in, wt_a, cj);
    rg_gates<<<dim3(2048), dim3(1024), 0, stream>>>(
        x, wt_in, wt_a, b_in, b_a, cj, aggA, aggE, packed);
    rg_scan<<<dim3(2048), dim3(1024), 0, stream>>>(packed, aggA, aggE, y);
}

// Round 4
// 339.261 us; speedup vs baseline: 1.2466x; 1.2466x over previous
//
#include <hip/hip_runtime.h>

#define B_ 8
#define T_ 4096
#define W_ 1024
#define H_ 8
#define BW_ 128
#define M_ 128          // timesteps per chunk
#define NC_ 32          // chunks per sequence (T_/M_)
#define XS 136          // LDS row stride (halves): 272B rows
#define NS_ 8           // 16-step segments per chunk

typedef __attribute__((ext_vector_type(8))) short bf16x8;
typedef __attribute__((ext_vector_type(4))) float f32x4;

__device__ __forceinline__ float bf2f(unsigned short u) {
    return __uint_as_float(((unsigned)u) << 16);
}
__device__ __forceinline__ unsigned short f2bf(float f) {
    unsigned u = __float_as_uint(f);
    u += 0x7fffu + ((u >> 16) & 1u);       // round-nearest-even
    return (unsigned short)(u >> 16);
}
__device__ __forceinline__ unsigned short f2h_bits(float f) {
    union { _Float16 h; unsigned short u; } cv;
    cv.h = (_Float16)f;
    return cv.u;
}
__device__ __forceinline__ float h2f(unsigned short u) {
    union { _Float16 h; unsigned short u; } cv;
    cv.u = u;
    return (float)cv.h;
}
__device__ __forceinline__ float sigmoidf_(float z) {
    return 1.0f / (1.0f + __expf(-z));
}

// ---------------- prep: fp32 weights -> transposed bf16 [h][j][i] in ws; cj = -8*softplus(a_param)
__global__ __launch_bounds__(256) void prep_kernel(
    const float* __restrict__ w_in, const float* __restrict__ w_a,
    const float* __restrict__ a_param,
    unsigned short* __restrict__ wt_in, unsigned short* __restrict__ wt_a,
    float* __restrict__ cj)
{
    int gid = blockIdx.x * 256 + threadIdx.x;     // 0..32767
    if (gid < W_) {
        float ap = a_param[gid];
        cj[gid] = -8.0f * log1pf(__expf(ap));
    }
    int mat  = gid >> 14;          // 0: w_in, 1: w_a
    int rem  = gid & 16383;
    int hh   = rem >> 11;          // head
    int r2   = rem & 2047;
    int seg  = r2 >> 7;            // i-segment (8 elems)
    int jrow = r2 & 127;           // output row j (low bits -> coalesced fp32 reads)
    const float* src = (mat ? w_a : w_in) + hh * BW_ * BW_;
    unsigned short* dst = (mat ? wt_a : wt_in) + hh * BW_ * BW_;
    unsigned short tmp[8] __attribute__((aligned(16)));
    #pragma unroll
    for (int k = 0; k < 8; ++k) tmp[k] = f2bf(src[(seg * 8 + k) * BW_ + jrow]);
    *(uint4*)(dst + jrow * BW_ + seg * 8) = *(const uint4*)tmp;
}

// ---------------- K1: gates (MFMA) + elementwise, computed ONCE.
// 512 threads, 8 waves; wave w owns cols [w*16, w*16+16), all 128 rows.
// B-fragments (both matrices) preloaded to 32 VGPRs per lane before X staging;
// 2 barriers; packed (a:fp16|nx:fp16) stored straight from registers.
__global__ __launch_bounds__(512, 4) void rg_gates(
    const float* __restrict__ x,
    const unsigned short* __restrict__ wt_in,
    const unsigned short* __restrict__ wt_a,
    const float* __restrict__ b_in,
    const float* __restrict__ b_a,
    const float* __restrict__ cj,
    float* __restrict__ aggA, float* __restrict__ aggE,
    unsigned int* __restrict__ packed)
{
    __shared__ alignas(16) unsigned short Xs[M_ * XS];    // 34816 B: x bf16
    __shared__ float2 S2[NS_ * BW_];                      //  8192 B: 16-step (A,E)
    __shared__ float cj_s[BW_], ba_s[BW_], bi_s[BW_];     //  1536 B

    const int tid = threadIdx.x;
    const int bid = blockIdx.x;
    const int c = bid & (NC_ - 1);
    const int s = bid >> 5;
    const int b = s >> 3;
    const int h = s & 7;
    const int t0 = c * M_;

    const int wave = tid >> 6;      // 0..7: column tile
    const int lane = tid & 63;
    const int q  = lane >> 4;
    const int cl = lane & 15;
    const int j  = wave * 16 + cl;  // output column

    // W register preload (issued before staging so latency hides under it)
    const unsigned short* wag = wt_a  + h * BW_ * BW_;
    const unsigned short* wig = wt_in + h * BW_ * BW_;
    bf16x8 bwa[4], bwi[4];
    #pragma unroll
    for (int kk = 0; kk < 4; ++kk) {
        size_t wo = (size_t)j * BW_ + kk * 32 + q * 8;
        bwa[kk] = *(const bf16x8*)(wag + wo);
        bwi[kk] = *(const bf16x8*)(wig + wo);
    }

    // stage X tile (fp32 -> bf16), coalesced 512B rows
    const float* xg = x + ((size_t)b * T_ + t0) * W_ + h * BW_;
    #pragma unroll
    for (int r = 0; r < 8; ++r) {
        int u = tid + r * 512;         // 0..4095
        int t = u >> 5, sg = u & 31;   // 4 floats per sg
        const float4 v = *(const float4*)(xg + (size_t)t * W_ + sg * 4);
        ushort4 hv;
        hv.x = f2bf(v.x); hv.y = f2bf(v.y); hv.z = f2bf(v.z); hv.w = f2bf(v.w);
        *(ushort4*)&Xs[t * XS + sg * 4] = hv;
    }
    if (tid < BW_) {
        cj_s[tid] = cj[h * BW_ + tid];
        ba_s[tid] = b_a[h * BW_ + tid];
        bi_s[tid] = b_in[h * BW_ + tid];
    }
    __syncthreads();

    f32x4 zero4 = {0.0f, 0.0f, 0.0f, 0.0f};
    f32x4 acc_a[8], acc_x[8];
    #pragma unroll
    for (int rt = 0; rt < 8; ++rt) { acc_a[rt] = zero4; acc_x[rt] = zero4; }

    // MFMA: kk outer (accumulate), rt inner (16 independent MFMAs per kk)
    #pragma unroll
    for (int kk = 0; kk < 4; ++kk) {
        #pragma unroll
        for (int rt = 0; rt < 8; ++rt) {
            bf16x8 af = *(const bf16x8*)&Xs[(rt * 16 + cl) * XS + kk * 32 + q * 8];
            acc_a[rt] = __builtin_amdgcn_mfma_f32_16x16x32_bf16(af, bwa[kk], acc_a[rt], 0, 0, 0);
            acc_x[rt] = __builtin_amdgcn_mfma_f32_16x16x32_bf16(af, bwi[kk], acc_x[rt], 0, 0, 0);
        }
    }

    // elementwise + packed store + shfl combine (4-step -> 16-step)
    unsigned int* pgc = packed + ((size_t)(s * NC_ + c) * M_) * BW_;
    const float cjv = cj_s[j], bav = ba_s[j], biv = bi_s[j];
    #pragma unroll
    for (int rt = 0; rt < 8; ++rt) {
        float A4 = 1.0f, E4 = 0.0f;
        #pragma unroll
        for (int r = 0; r < 4; ++r) {
            int tl = rt * 16 + q * 4 + r;                       // C/D layout: row = q*4 + r
            float la = cjv * sigmoidf_(acc_a[rt][r] + bav);     // log_a <= 0
            float a  = __expf(la);
            float gx = sigmoidf_(acc_x[rt][r] + biv);
            float xv = bf2f(Xs[tl * XS + j]);
            float mult = sqrtf(fmaxf(1.0f - a * a, 0.0f));
            if (t0 + tl == 0) { a = 0.0f; mult = 1.0f; }        // reset at global t=0
            float nxv = xv * gx * mult;
            unsigned short nxb = f2h_bits(nxv);
            float nxr = h2f(nxb);
            E4 = fmaf(a, E4, nxr);
            A4 *= a;
            pgc[(size_t)tl * BW_ + j] = ((unsigned int)f2h_bits(a) << 16) | (unsigned int)nxb;
        }
        // combine across q (lanes 16 apart): stage 1 pairs (q0,q1),(q2,q3); stage 2 full
        float Ap = __shfl_xor(A4, 16);
        float Ep = __shfl_xor(E4, 16);
        float E8 = ((lane >> 4) & 1) ? fmaf(A4, Ep, E4) : fmaf(Ap, E4, Ep);
        float A8 = A4 * Ap;
        Ap = __shfl_xor(A8, 32);
        Ep = __shfl_xor(E8, 32);
        float E16 = ((lane >> 5) & 1) ? fmaf(A8, Ep, E8) : fmaf(Ap, E8, Ep);
        float A16 = A8 * Ap;
        if ((lane >> 4) == 0) S2[rt * BW_ + j] = make_float2(A16, E16);
    }
    __syncthreads();

    // chunk aggregate write
    if (tid < BW_) {
        float At = 1.0f, Et = 0.0f;
        #pragma unroll
        for (int s8 = 0; s8 < NS_; ++s8) {
            float2 v = S2[s8 * BW_ + tid];
            Et = fmaf(v.x, Et, v.y);
            At *= v.x;
        }
        size_t idx = ((size_t)s * NC_ + c) * BW_ + tid;
        aggA[idx] = At;
        aggE[idx] = Et;
    }
}

// ---------------- K2: streaming scan + replay; uint2-vectorized (2 j per thread);
// per-block carry fold (no separate carry_scan kernel)
__global__ __launch_bounds__(512, 4) void rg_scan(
    const unsigned int* __restrict__ packed,
    const float* __restrict__ aggA, const float* __restrict__ aggE,
    float* __restrict__ y)
{
    __shared__ float2 S2[NS_ * BW_];   // 8 KB
    __shared__ float qin[NS_ * BW_];   // 4 KB

    const int tid = threadIdx.x;
    const int bid = blockIdx.x;
    const int c = bid & (NC_ - 1);
    const int s = bid >> 5;
    const int b = s >> 3;
    const int h = s & 7;

    // chunk-blocked packed: contiguous 64KB per block
    const uint2* pg = (const uint2*)(packed + ((size_t)(s * NC_ + c) * M_) * BW_);
    const int j2 = tid & 63;           // pair of adjacent j
    const int qq = tid >> 6;           // 16-step segment 0..7
    const int jb = j2 * 2;

    uint2 v[16];
    #pragma unroll
    for (int i = 0; i < 16; ++i)
        v[i] = pg[(size_t)(qq * 16 + i) * 64 + j2];

    float A0 = 1.0f, E0 = 0.0f, A1 = 1.0f, E1 = 0.0f;
    #pragma unroll
    for (int i = 0; i < 16; ++i) {
        float a0  = h2f((unsigned short)(v[i].x >> 16));
        float n0  = h2f((unsigned short)(v[i].x & 0xffffu));
        float a1  = h2f((unsigned short)(v[i].y >> 16));
        float n1  = h2f((unsigned short)(v[i].y & 0xffffu));
        E0 = fmaf(a0, E0, n0);  A0 *= a0;
        E1 = fmaf(a1, E1, n1);  A1 *= a1;
    }
    S2[qq * BW_ + jb]     = make_float2(A0, E0);
    S2[qq * BW_ + jb + 1] = make_float2(A1, E1);
    __syncthreads();

    if (tid < 64) {
        // fold chunk aggregates 0..c-1 (identical order to original carry_scan)
        const float* pA = aggA + (size_t)s * NC_ * BW_;
        const float* pE = aggE + (size_t)s * NC_ * BW_;
        float h0 = 0.0f, h1 = 0.0f;
        for (int cc = 0; cc < c; ++cc) {
            const float2 a2 = *(const float2*)(pA + (size_t)cc * BW_ + tid * 2);
            const float2 e2 = *(const float2*)(pE + (size_t)cc * BW_ + tid * 2);
            h0 = fmaf(a2.x, h0, e2.x);
            h1 = fmaf(a2.y, h1, e2.y);
        }
        #pragma unroll
        for (int s8 = 0; s8 < NS_; ++s8) {
            qin[s8 * BW_ + tid * 2]     = h0;
            qin[s8 * BW_ + tid * 2 + 1] = h1;
            float2 g0 = S2[s8 * BW_ + tid * 2];
            float2 g1 = S2[s8 * BW_ + tid * 2 + 1];
            h0 = fmaf(g0.x, h0, g0.y);
            h1 = fmaf(g1.x, h1, g1.y);
        }
    }
    __syncthreads();

    float h0 = qin[qq * BW_ + jb];
    float h1 = qin[qq * BW_ + jb + 1];
    float* yg = y + ((size_t)b * T_ + c * M_) * W_ + h * BW_ + jb;
    #pragma unroll
    for (int i = 0; i < 16; ++i) {
        float a0  = h2f((unsigned short)(v[i].x >> 16));
        float n0  = h2f((unsigned short)(v[i].x & 0xffffu));
        float a1  = h2f((unsigned short)(v[i].y >> 16));
        float n1  = h2f((unsigned short)(v[i].y & 0xffffu));
        h0 = fmaf(a0, h0, n0);
        h1 = fmaf(a1, h1, n1);
        float2 out = make_float2(h0, h1);
        *(float2*)(yg + (size_t)(qq * 16 + i) * W_) = out;   // 512B contiguous per wave-instr
    }
}

extern "C" void kernel_launch(void* const* d_in, const int* in_sizes, int n_in,
                              void* d_out, int out_size, void* d_ws, size_t ws_size,
                              hipStream_t stream)
{
    const float* x     = (const float*)d_in[0];
    const float* w_in  = (const float*)d_in[1];
    const float* b_in  = (const float*)d_in[2];
    const float* w_a   = (const float*)d_in[3];
    const float* b_a   = (const float*)d_in[4];
    const float* a_par = (const float*)d_in[5];
    float* y = (float*)d_out;

    char* ws = (char*)d_ws;
    unsigned short* wt_in = (unsigned short*)(ws);
    unsigned short* wt_a  = (unsigned short*)(ws + 262144);
    float* cj    = (float*)(ws + 524288);
    float* aggA  = (float*)(ws + 528384);
    float* aggE  = (float*)(ws + 1576960);
    unsigned int* packed = (unsigned int*)(ws + 2625536);

    const size_t NEED = 2625536ull + (size_t)B_ * T_ * W_ * 4ull;   // +128 MB packed
    if (ws_size < NEED) return;

    prep_kernel<<<dim3(128), dim3(256), 0, stream>>>(w_in, w_a, a_par, wt_in, wt_a, cj);
    rg_gates<<<dim3(2048), dim3(512), 0, stream>>>(
        x, wt_in, wt_a, b_in, b_a, cj, aggA, aggE, packed);
    rg_scan<<<dim3(2048), dim3(512), 0, stream>>>(packed, aggA, aggE, y);
}